// Round 11
// baseline (299.444 us; speedup 1.0000x reference)
//
#include <hip/hip_runtime.h>

// SkeletonConv: out[b,o,h,w] = sum_{c,k} W[o,c,k] * x[b,c, h+(k-1)*step, w+(k-1)*dil]
// B=64, C_in=C_out=16, K=3, H=W=256, fp32.
// R11: R10 structure (o-split x2, ALL-16-c upfront burst -> one counted-vmcnt
//      chain -> single 1536-FMA block) + amdgpu_waves_per_eu(4,4) to PIN the
//      register budget at 128. Lesson R6/R9/R10: launch_bounds' 2nd arg is only
//      a cap; the allocator's occupancy heuristic still picked 64 (R10: spill,
//      WRITE +49MB) or 20 (R9: AGPR shuttle). waves_per_eu(4,4) fixes min=max.
//      Ledger: R1 157 / R2 2660 / R3 272 / R4 477 / R5 387 / R6 148 /
//              R7 114.7 best / R8 127.9 / R9 167 / R10 237 (spill @VGPR=64).

constexpr int CIN = 16, COUT = 16, KK = 3, H = 256, W = 256;
constexpr int WT  = 4;            // w-elements per thread (float4)
constexpr int TPR = W / WT;       // 64 threads = one wave per (b,h,half) row
constexpr int OSPLIT = 2, OPT = COUT / OSPLIT;   // 8 output channels per thread

typedef float f4 __attribute__((ext_vector_type(4)));

__global__ __launch_bounds__(256)
__attribute__((amdgpu_waves_per_eu(4, 4)))       // pin: exactly 128 VGPR budget
void skel_conv_kernel(const float* __restrict__ x, const float* __restrict__ wgt,
                      const int* __restrict__ dil_p, const int* __restrict__ step_p,
                      float* __restrict__ out, int B)
{
    const int dil  = dil_p[0];
    const int step = step_p[0];

    const int tid  = blockIdx.x * blockDim.x + threadIdx.x;
    const int lane = tid & (TPR - 1);            // lane-in-wave; wave spans a row
    int idx = tid / TPR;                         // (b, h, half)
    const int half = idx & (OSPLIT - 1);         // both halves of a row in one block
    idx >>= 1;
    const int h = idx & (H - 1);
    const int b = idx >> 8;
    if (b >= B) return;
    const int w0    = lane * WT;
    const int obase = half * OPT;

    float acc[OPT][WT];
    #pragma unroll
    for (int o = 0; o < OPT; ++o)
        #pragma unroll
        for (int j = 0; j < WT; ++j) acc[o][j] = 0.f;

    const size_t cs = (size_t)H * W;
    const float* xr = x + (size_t)b * CIN * cs + (size_t)h * W + w0;

    if (dil == 1 && step == 0) {
        const bool l0 = (lane == 0), lN = (lane == TPR - 1);

        // ---- one burst: all 16 channel f4's, fully independent loads ----
        f4 v[CIN];
        #pragma unroll
        for (int c = 0; c < CIN; ++c)
            v[c] = *(const f4*)(xr + (size_t)c * cs);   // static idx -> registers

        // ---- one compute block: 16c x 8o x 4w x 3k = 1536 FMA ----
        #pragma unroll
        for (int c = 0; c < CIN; ++c) {
            float left  = __shfl_up(v[c].w, 1);         // x[w0-1]
            float right = __shfl_down(v[c].x, 1);       // x[w0+4]
            if (l0) left  = 0.f;                        // zero padding
            if (lN) right = 0.f;
            #pragma unroll
            for (int o = 0; o < OPT; ++o) {
                const float* wq = wgt + ((size_t)(obase + o) * CIN + c) * KK;
                const float a0 = wq[0], a1 = wq[1], a2 = wq[2];   // uniform -> s_load
                acc[o][0] = fmaf(a0, left,   acc[o][0]);
                acc[o][0] = fmaf(a1, v[c].x, acc[o][0]);
                acc[o][0] = fmaf(a2, v[c].y, acc[o][0]);
                acc[o][1] = fmaf(a0, v[c].x, acc[o][1]);
                acc[o][1] = fmaf(a1, v[c].y, acc[o][1]);
                acc[o][1] = fmaf(a2, v[c].z, acc[o][1]);
                acc[o][2] = fmaf(a0, v[c].y, acc[o][2]);
                acc[o][2] = fmaf(a1, v[c].z, acc[o][2]);
                acc[o][2] = fmaf(a2, v[c].w, acc[o][2]);
                acc[o][3] = fmaf(a0, v[c].z, acc[o][3]);
                acc[o][3] = fmaf(a1, v[c].w, acc[o][3]);
                acc[o][3] = fmaf(a2, right,  acc[o][3]);
            }
        }
    } else {
        // Generic path: clamped loads + select (never faults, any dil/step).
        #pragma unroll 1
        for (int c = 0; c < CIN; ++c) {
            const float* xc = x + (size_t)b * CIN * cs + (size_t)c * cs;
            #pragma unroll
            for (int k = 0; k < KK; ++k) {
                const int off = k - KK / 2;
                const int hh  = h + off * step;
                const bool rowok = (hh >= 0) && (hh < H);
                const int hcl = hh < 0 ? 0 : (hh > H - 1 ? H - 1 : hh);
                float t[WT];
                #pragma unroll
                for (int j = 0; j < WT; ++j) {
                    const int ww  = w0 + j + off * dil;
                    const bool ok = rowok && (ww >= 0) && (ww < W);
                    const int wcl = ww < 0 ? 0 : (ww > W - 1 ? W - 1 : ww);
                    const float vv = xc[(size_t)hcl * W + wcl];
                    t[j] = ok ? vv : 0.f;
                }
                #pragma unroll
                for (int o = 0; o < OPT; ++o) {
                    const float wk = wgt[((size_t)(obase + o) * CIN + c) * KK + k];
                    #pragma unroll
                    for (int j = 0; j < WT; ++j)
                        acc[o][j] = fmaf(wk, t[j], acc[o][j]);
                }
            }
        }
    }

    float* orow = out + ((size_t)b * COUT + obase) * cs + (size_t)h * W + w0;
    #pragma unroll
    for (int o = 0; o < OPT; ++o) {
        f4 r = {acc[o][0], acc[o][1], acc[o][2], acc[o][3]};
        *(f4*)(orow + (size_t)o * cs) = r;       // coalesced dwordx4
    }
}

extern "C" void kernel_launch(void* const* d_in, const int* in_sizes, int n_in,
                              void* d_out, int out_size, void* d_ws, size_t ws_size,
                              hipStream_t stream) {
    const float* x    = (const float*)d_in[0];
    const float* wgt  = (const float*)d_in[1];
    const int*   dil  = (const int*)d_in[2];
    const int*   step = (const int*)d_in[3];
    float*       out  = (float*)d_out;

    const int B = in_sizes[0] / (CIN * H * W);
    const int total = B * H * OSPLIT * TPR;      // one thread per 4 w's per o-half
    const int block = 256;
    const int grid  = (total + block - 1) / block;

    skel_conv_kernel<<<grid, block, 0, stream>>>(x, wgt, dil, step, out, B);
}

// Round 12
// 120.949 us; speedup vs baseline: 2.4758x; 2.4758x over previous
//
#include <hip/hip_runtime.h>

// SkeletonConv: out[b,o,h,w] = sum_{c,k} W[o,c,k] * x[b,c, h+(k-1)*step, w+(k-1)*dil]
// B=64, C_in=C_out=16, K=3, H=W=256, fp32.
// R12: R7 (best, 114.7us) + weight repack to c-major [c][o][k] so each c's 48
//      weights are CONTIGUOUS -> compiler merges to s_load_dwordx8 x6 (vs 16+
//      strided s_loads per c whose lgkm latency gated each 12-FMA cluster).
//      Single-variable change; FMA order identical -> absmax bit-identical.
//      Allocator lore: picks 64 VGPR regardless of hints; (256,4) is the only
//      benign config (R2/R9/R11 hints -> spill/shuttle). Ledger: R1 157 /
//      R2 2660 / R3 272 / R4 477 / R5 387 / R6 148 / R7 114.7 / R8 127.9 /
//      R9 167 / R10 237 / R11 299.

constexpr int CIN = 16, COUT = 16, KK = 3, H = 256, W = 256;
constexpr int WT  = 4;            // w-elements per thread (float4)
constexpr int TPR = W / WT;       // 64 threads = one wave per (b,h) row
constexpr int CHUNK = 4;          // c-channels per pipeline stage

typedef float f4 __attribute__((ext_vector_type(4)));

// Repack W[o][c][k] -> wrep[c][o][k] (48 contiguous floats per c).
__global__ __launch_bounds__(256)
void repack_w_kernel(const float* __restrict__ wgt, float* __restrict__ wrep) {
    const int t = blockIdx.x * blockDim.x + threadIdx.x;
    if (t < COUT * CIN * KK) {
        const int o = t / (CIN * KK);
        const int r = t % (CIN * KK);
        const int c = r / KK;
        const int k = r % KK;
        wrep[(c * COUT + o) * KK + k] = wgt[t];
    }
}

__global__ __launch_bounds__(256, 4)   // R7's proven-benign config
void skel_conv_kernel(const float* __restrict__ x, const float* __restrict__ wrep,
                      const float* __restrict__ wgt,
                      const int* __restrict__ dil_p, const int* __restrict__ step_p,
                      float* __restrict__ out, int B)
{
    const int dil  = dil_p[0];
    const int step = step_p[0];

    const int tid  = blockIdx.x * blockDim.x + threadIdx.x;
    const int lane = tid & (TPR - 1);            // lane-in-wave; wave spans a row
    const int idx  = tid / TPR;
    const int h    = idx & (H - 1);
    const int b    = idx >> 8;
    if (b >= B) return;
    const int w0 = lane * WT;

    float acc[COUT][WT];
    #pragma unroll
    for (int o = 0; o < COUT; ++o)
        #pragma unroll
        for (int j = 0; j < WT; ++j) acc[o][j] = 0.f;

    const size_t cs = (size_t)H * W;
    const float* xr = x + (size_t)b * CIN * cs + (size_t)h * W + w0;

    if (dil == 1 && step == 0) {
        const bool l0 = (lane == 0), lN = (lane == TPR - 1);

        auto compute_c = [&](int c, f4 v) {      // c is wave-uniform
            float left  = __shfl_up(v.w, 1);     // x[w0-1]
            float right = __shfl_down(v.x, 1);   // x[w0+4]
            if (l0) left  = 0.f;                 // zero padding
            if (lN) right = 0.f;
            const float t[6] = {left, v.x, v.y, v.z, v.w, right};  // static idx only
            const float* wc = wrep + c * (COUT * KK);  // 48 CONTIGUOUS floats
            #pragma unroll
            for (int o = 0; o < COUT; ++o) {
                const float a0 = wc[o * KK + 0];       // merges to s_load_dwordx8
                const float a1 = wc[o * KK + 1];
                const float a2 = wc[o * KK + 2];
                #pragma unroll
                for (int j = 0; j < WT; ++j) {   // exactly 3 v_fma_f32 per (o,j)
                    acc[o][j] = fmaf(a0, t[j],     acc[o][j]);
                    acc[o][j] = fmaf(a1, t[j + 1], acc[o][j]);
                    acc[o][j] = fmaf(a2, t[j + 2], acc[o][j]);
                }
            }
        };

        // prologue: chunk 0 in flight
        f4 p0 = *(const f4*)(xr + 0 * cs);
        f4 p1 = *(const f4*)(xr + 1 * cs);
        f4 p2 = *(const f4*)(xr + 2 * cs);
        f4 p3 = *(const f4*)(xr + 3 * cs);

        #pragma unroll 1
        for (int cc = 0; cc < CIN / CHUNK; ++cc) {
            // issue next chunk's 4 independent loads (last iter re-reads, L1 hit)
            const int nc = (cc + 1 < CIN / CHUNK) ? (cc + 1) * CHUNK : cc * CHUNK;
            const float* nx = xr + (size_t)nc * cs;
            f4 v0 = *(const f4*)(nx + 0 * cs);
            f4 v1 = *(const f4*)(nx + 1 * cs);
            f4 v2 = *(const f4*)(nx + 2 * cs);
            f4 v3 = *(const f4*)(nx + 3 * cs);

            // compute current chunk: 4 c x 16 o x 4 w x 3 k = 768 FMA
            const int cb = cc * CHUNK;
            compute_c(cb + 0, p0);
            compute_c(cb + 1, p1);
            compute_c(cb + 2, p2);
            compute_c(cb + 3, p3);

            p0 = v0; p1 = v1; p2 = v2; p3 = v3;
        }
    } else {
        // Generic path: clamped loads + select (never faults, any dil/step).
        #pragma unroll 1
        for (int c = 0; c < CIN; ++c) {
            const float* xc = x + (size_t)b * CIN * cs + (size_t)c * cs;
            #pragma unroll
            for (int k = 0; k < KK; ++k) {
                const int off = k - KK / 2;
                const int hh  = h + off * step;
                const bool rowok = (hh >= 0) && (hh < H);
                const int hcl = hh < 0 ? 0 : (hh > H - 1 ? H - 1 : hh);
                float t[WT];
                #pragma unroll
                for (int j = 0; j < WT; ++j) {
                    const int ww  = w0 + j + off * dil;
                    const bool ok = rowok && (ww >= 0) && (ww < W);
                    const int wcl = ww < 0 ? 0 : (ww > W - 1 ? W - 1 : ww);
                    const float vv = xc[(size_t)hcl * W + wcl];
                    t[j] = ok ? vv : 0.f;
                }
                #pragma unroll
                for (int o = 0; o < COUT; ++o) {
                    const float wk = wgt[((size_t)o * CIN + c) * KK + k];
                    #pragma unroll
                    for (int j = 0; j < WT; ++j)
                        acc[o][j] = fmaf(wk, t[j], acc[o][j]);
                }
            }
        }
    }

    float* orow = out + (size_t)b * COUT * cs + (size_t)h * W + w0;
    #pragma unroll
    for (int o = 0; o < COUT; ++o) {
        f4 r = {acc[o][0], acc[o][1], acc[o][2], acc[o][3]};
        *(f4*)(orow + (size_t)o * cs) = r;       // coalesced dwordx4
    }
}

extern "C" void kernel_launch(void* const* d_in, const int* in_sizes, int n_in,
                              void* d_out, int out_size, void* d_ws, size_t ws_size,
                              hipStream_t stream) {
    const float* x    = (const float*)d_in[0];
    const float* wgt  = (const float*)d_in[1];
    const int*   dil  = (const int*)d_in[2];
    const int*   step = (const int*)d_in[3];
    float*       out  = (float*)d_out;
    float*       wrep = (float*)d_ws;            // 768 floats = 3 KB scratch

    repack_w_kernel<<<3, 256, 0, stream>>>(wgt, wrep);

    const int B = in_sizes[0] / (CIN * H * W);
    const int total = B * H * TPR;               // one thread per 4 output w's
    const int block = 256;
    const int grid  = (total + block - 1) / block;

    skel_conv_kernel<<<grid, block, 0, stream>>>(x, wrep, wgt, dil, step, out, B);
}